// Round 1
// baseline (511.728 us; speedup 1.0000x reference)
//
#include <hip/hip_runtime.h>

// GraphPool: out[i] = max(A[i], max_j A[adj_d[i - d*PER_DEG][j]]) where d = i / PER_DEG.
// Layout: 440000 rows x 128 fp32 features. Degrees 0..10, 40000 rows each, contiguous.
#define N_ATOMS 440000
#define F_DIM   128
#define PER_DEG 40000
#define MAX_DEG 10

// 10 adjacency pointers passed by value as a kernel argument (no device alloc needed).
struct AdjPtrs { const int* p[MAX_DEG]; };

// 256 threads/block = 8 rows/block, 32 lanes per row, one float4 (4 features) per lane.
// Degree is wave-uniform: 2 rows per wave, degree changes only at row multiples of 40000.
__global__ __launch_bounds__(256) void graphpool_kernel(
    const float4* __restrict__ A,   // atom_features viewed as float4, row stride 32
    AdjPtrs adj,
    float4* __restrict__ out)
{
    const int tid  = blockIdx.x * 256 + threadIdx.x;
    const int row  = tid >> 5;        // output row
    const int lane = tid & 31;        // float4 slot within the row
    if (row >= N_ATOMS) return;

    const int d     = row / PER_DEG;            // 0..10 (magic-mul, wave-uniform)
    const int local = row - d * PER_DEG;

    const size_t rbase = (size_t)row * (F_DIM / 4);
    float4 v = A[rbase + lane];                 // self features

    if (d > 0) {
        const int* idx = adj.p[d - 1] + (size_t)local * d;

        // Prefetch all indices first (contiguous ints, broadcast across the 32 lanes),
        // so the gather loads below are independent and can all be in flight at once.
        int nbrs[MAX_DEG];
        #pragma unroll
        for (int j = 0; j < MAX_DEG; ++j) {
            if (j < d) nbrs[j] = idx[j];
        }

        #pragma unroll
        for (int j = 0; j < MAX_DEG; ++j) {
            if (j < d) {
                const float4 nv = A[(size_t)nbrs[j] * (F_DIM / 4) + lane];
                v.x = fmaxf(v.x, nv.x);
                v.y = fmaxf(v.y, nv.y);
                v.z = fmaxf(v.z, nv.z);
                v.w = fmaxf(v.w, nv.w);
            }
        }
    }

    out[rbase + lane] = v;
}

extern "C" void kernel_launch(void* const* d_in, const int* in_sizes, int n_in,
                              void* d_out, int out_size, void* d_ws, size_t ws_size,
                              hipStream_t stream) {
    // d_in[0] = atom_features (float32, 440000*128)
    // d_in[1] = deg_slice (int32, 11x2) -- structure is fixed by setup_inputs; not needed
    // d_in[2..11] = adj1..adj10 (int32, 40000*d each)
    const float4* A = (const float4*)d_in[0];
    AdjPtrs adj;
    for (int i = 0; i < MAX_DEG; ++i) adj.p[i] = (const int*)d_in[2 + i];
    float4* out = (float4*)d_out;

    const int total_threads = N_ATOMS * 32;      // 32 lanes per row
    const int blocks = (total_threads + 255) / 256;
    graphpool_kernel<<<blocks, 256, 0, stream>>>(A, adj, out);
}